// Round 8
// baseline (2378.644 us; speedup 1.0000x reference)
//
#include <hip/hip_runtime.h>

#define VV 32000
#define EE 256
#define HH 512
#define BB 32
#define SS 80
#define TT 80
// comb rows: [t:80][b:32] = 2560 rows of 1024 fp16; t=79 rows are pad (unwritten)

typedef __attribute__((ext_vector_type(8))) _Float16 half8;
typedef __attribute__((ext_vector_type(4))) _Float16 half4;
typedef __attribute__((ext_vector_type(4))) float floatx4;
typedef unsigned long long u64;

__device__ __forceinline__ void gload16(const _Float16* g, _Float16* l) {
  __builtin_amdgcn_global_load_lds((const __attribute__((address_space(1))) void*)g,
                                   (__attribute__((address_space(3))) void*)l, 16, 0, 0);
}

__device__ __forceinline__ u64 aload(const u64* p) {
  return __hip_atomic_load(p, __ATOMIC_RELAXED, __HIP_MEMORY_SCOPE_AGENT);
}
__device__ __forceinline__ void astore(u64* p, u64 v) {
  __hip_atomic_store(p, v, __ATOMIC_RELAXED, __HIP_MEMORY_SCOPE_AGENT);
}

__device__ __forceinline__ float dot8(half8 a, half8 b, float c) {
  typedef __attribute__((ext_vector_type(2))) _Float16 half2v;
  half2v a0 = {a[0],a[1]}, a1 = {a[2],a[3]}, a2 = {a[4],a[5]}, a3 = {a[6],a[7]};
  half2v b0 = {b[0],b[1]}, b1 = {b[2],b[3]}, b2 = {b[4],b[5]}, b3 = {b[6],b[7]};
  c = __builtin_amdgcn_fdot2(a0, b0, c, false);
  c = __builtin_amdgcn_fdot2(a1, b1, c, false);
  c = __builtin_amdgcn_fdot2(a2, b2, c, false);
  c = __builtin_amdgcn_fdot2(a3, b3, c, false);
  return c;
}

__device__ __forceinline__ float sigm(float x) { return 1.f/(1.f + __expf(-x)); }
__device__ __forceinline__ float tanh_f(float x) { return 2.f/(1.f + __expf(-2.f*x)) - 1.f; }

// ---------------- embedding gather (fp32 -> fp16 rows) ----------------
__global__ __launch_bounds__(256) void embed_gather(
    const int* __restrict__ src, const int* __restrict__ tgt,
    const float* __restrict__ emb,
    _Float16* __restrict__ xsrc, _Float16* __restrict__ xdec)
{
  const int r = blockIdx.x;
  const int e = threadIdx.x; // EE == 256
  if (r < 2560) {
    const int tok = src[r];
    xsrc[(size_t)r*EE + e] = (_Float16)emb[(size_t)tok*EE + e];
  } else {
    const int rr = r - 2560;
    if (rr < 2528) {
      const int b = rr / 79, t = rr - b*79;
      const int tok = tgt[b*TT + t];
      xdec[(size_t)rr*EE + e] = (_Float16)emb[(size_t)tok*EE + e];
    } else {
      xdec[(size_t)rr*EE + e] = (_Float16)0.f;
    }
  }
}

// ---------------- weight fp32 -> fp16 conversion (Wih, out_W) ----------------
__global__ __launch_bounds__(256) void wconv(
    const float* __restrict__ we, const float* __restrict__ wd, const float* __restrict__ ow,
    _Float16* __restrict__ weh, _Float16* __restrict__ wdh, _Float16* __restrict__ owh)
{
  const long n1 = 1536L*256;
  const long total = 2*n1 + (long)VV*1024;
  for (long i = (long)blockIdx.x*256 + threadIdx.x; i < total; i += (long)gridDim.x*256) {
    if (i < n1)           weh[i]        = (_Float16)we[i];
    else if (i < 2*n1)    wdh[i-n1]     = (_Float16)wd[i-n1];
    else                  owh[i-2*n1]   = (_Float16)ow[i-2*n1];
  }
}

// ---------------- fp16 MFMA GEMM (MODE 0 only): C = A * B^T + bias ----------
__global__ __launch_bounds__(256) void mfma_gemm(
    const _Float16* __restrict__ A, int lda,
    const _Float16* __restrict__ Bm, int ldb,
    const float* __restrict__ bias,
    float* __restrict__ Cout, int ldc, int K)
{
  __shared__ _Float16 As[4096];  // 128 x 32
  __shared__ _Float16 Bs[4096];  // 128 x 32
  const int tid = threadIdx.x;
  const int lane = tid & 63;
  const int wv = tid >> 6;
  const int wr = wv >> 1, wc = wv & 1;
  const int mt = blockIdx.y, nt = blockIdx.x;
  floatx4 acc[4][4];
#pragma unroll
  for (int i=0;i<4;++i)
#pragma unroll
    for (int j=0;j<4;++j) acc[i][j] = (floatx4){0.f,0.f,0.f,0.f};
  const int srow = lane >> 2;
  const int scol = (lane & 3) * 8;
  const _Float16* Ab = A + (size_t)(mt*128)*lda;
  const _Float16* Bb = Bm + (size_t)(nt*128)*ldb;
  const int g8 = (lane >> 4) * 8;
  const int lr = lane & 15;
  for (int kb = 0; kb < K; kb += 32) {
    __syncthreads();
#pragma unroll
    for (int cc = 0; cc < 2; ++cc) {
      const int c = wv*2 + cc;
      gload16(Ab + (size_t)(c*16 + srow)*lda + kb + scol, As + c*512);
      gload16(Bb + (size_t)(c*16 + srow)*ldb + kb + scol, Bs + c*512);
    }
    __syncthreads();
    half8 af[4], bf[4];
#pragma unroll
    for (int i=0;i<4;++i) af[i] = *(const half8*)(As + (wr*64 + i*16 + lr)*32 + g8);
#pragma unroll
    for (int j=0;j<4;++j) bf[j] = *(const half8*)(Bs + (wc*64 + j*16 + lr)*32 + g8);
#pragma unroll
    for (int i=0;i<4;++i)
#pragma unroll
      for (int j=0;j<4;++j)
        acc[i][j] = __builtin_amdgcn_mfma_f32_16x16x32_f16(af[i], bf[j], acc[i][j], 0,0,0);
  }
  const int rm = 4*(lane>>4);
#pragma unroll
  for (int i=0;i<4;++i) {
#pragma unroll
    for (int r=0;r<4;++r) {
      const int row = mt*128 + wr*64 + i*16 + rm + r;
#pragma unroll
      for (int j=0;j<4;++j) {
        const int col = nt*128 + wc*64 + j*16 + lr;
        Cout[(size_t)row*ldc + col] = acc[i][j][r] + bias[col];
      }
    }
  }
}

// ---------------- persistent fused kernel -----------------------------------
// grid 224 x 128 thr, 133.5KB dyn LDS (1 WG/CU).
//   WGs 0..31  : producers -- r4-proven flags recurrence (enc 80 + dec 79),
//                LDS-resident Whh slice, LDS eo stash, deferred attention.
//                comb rows written sc1 in [t][b] layout; per-WG prog counter.
//                After finishing, producers join the GEMM ticket pool.
//   WGs 32..223: workers -- claim tiles (ticket), wait until tile's 4 t-rows
//                are published by ALL producers, compute 128x128 logits tile,
//                scatter to out[b, t+1, :]; t=79 pad rows -> out[b,0,:] = 0.
// Deadlock-free: producers never wait on workers; 192 workers + 32 producers
// = 224 <= 224 CUs so producers are always resident regardless of dispatch
// order; if workers never run, producers mop up all tiles at the end.
#define SEQ_SMEM ((48*520 + 80*512 + 512)*2 + 160*4)
#define NTILN 250            // 32000/128
#define NTILES (20*NTILN)    // 2560/128 row-tiles x col-tiles
__global__ __launch_bounds__(128) void seq_over(
    const float* __restrict__ eWhh, const float* __restrict__ dWhh,
    const float* __restrict__ ebhh, const float* __restrict__ dbhh,
    const float* __restrict__ giE, const float* __restrict__ giD,
    _Float16* __restrict__ h16,    // ping-pong 2 x 32 x 512 fp16
    _Float16* __restrict__ comb,   // [80][32][1024] fp16
    unsigned* __restrict__ flags,  // [2][32] monotone counters, 128B apart
    unsigned* __restrict__ prog,   // [32] comb-rows-done counters, 128B apart
    unsigned* __restrict__ tick,   // tile ticket counter
    const _Float16* __restrict__ oWh, const float* __restrict__ outb,
    float* __restrict__ out)
{
  extern __shared__ char smem[];
  __shared__ unsigned s_id;
  const int wg  = blockIdx.x;
  const int tid = threadIdx.x;
  const int lane = tid & 63;
  const int wv = tid >> 6;

  // ---------------- shared tile routine (workers + producer mop-up) ---------
  auto wait_prog = [&](unsigned tgt){
    if (wv == 0) {
      const unsigned* pp = prog + (lane & 31)*32;
      for (;;) {
        unsigned v = __hip_atomic_load(pp, __ATOMIC_RELAXED, __HIP_MEMORY_SCOPE_AGENT);
        if (__all_sync(0xFFFFFFFFFFFFFFFFull, v >= tgt)) break;
        __builtin_amdgcn_s_sleep(32);
      }
    }
    __syncthreads();
  };
  auto do_tile = [&](int mt, int nt){
    _Float16* As = (_Float16*)smem;      // 128 x 32
    _Float16* Bs = As + 4096;            // 128 x 32
    const int srow = lane >> 2;
    const int scol = (lane & 3) * 8;
    const int g8 = (lane >> 4) * 8;
    const int lr = lane & 15;
    const int rm = 4*(lane>>4);
    floatx4 acc[4][8];
#pragma unroll
    for (int i=0;i<4;++i)
#pragma unroll
      for (int j=0;j<8;++j) acc[i][j] = (floatx4){0.f,0.f,0.f,0.f};
    const _Float16* Ab = comb + (size_t)(mt*128)*1024;
    const _Float16* Bb = oWh  + (size_t)(nt*128)*1024;
    for (int kb = 0; kb < 1024; kb += 32) {
      __syncthreads();
#pragma unroll
      for (int cc = 0; cc < 4; ++cc) {
        const int c = wv*4 + cc;
        gload16(Ab + (size_t)(c*16 + srow)*1024 + kb + scol, As + c*512);
        gload16(Bb + (size_t)(c*16 + srow)*1024 + kb + scol, Bs + c*512);
      }
      __syncthreads();
      half8 af[4], bf[8];
#pragma unroll
      for (int i=0;i<4;++i) af[i] = *(const half8*)(As + (wv*64 + i*16 + lr)*32 + g8);
#pragma unroll
      for (int j=0;j<8;++j) bf[j] = *(const half8*)(Bs + (j*16 + lr)*32 + g8);
#pragma unroll
      for (int i=0;i<4;++i)
#pragma unroll
        for (int j=0;j<8;++j)
          acc[i][j] = __builtin_amdgcn_mfma_f32_16x16x32_f16(af[i], bf[j], acc[i][j], 0,0,0);
    }
    float bj[8];
#pragma unroll
    for (int j=0;j<8;++j) bj[j] = outb[nt*128 + j*16 + lr];
#pragma unroll
    for (int i=0;i<4;++i) {
#pragma unroll
      for (int r=0;r<4;++r) {
        const int row = mt*128 + wv*64 + i*16 + rm + r;
        const int t = row >> 5, b = row & 31;
        float* orow = out + ((size_t)(b*80) + (t < 79 ? t+1 : 0))*VV + nt*128;
#pragma unroll
        for (int j=0;j<8;++j) {
          const int col = j*16 + lr;
          orow[col] = (t < 79) ? (acc[i][j][r] + bj[j]) : 0.f;
        }
      }
    }
  };
  auto tile_pool = [&](){
    for (;;) {
      if (tid == 0)
        s_id = __hip_atomic_fetch_add(tick, 1u, __ATOMIC_RELAXED, __HIP_MEMORY_SCOPE_AGENT);
      __syncthreads();
      const unsigned id = s_id;
      if (id >= NTILES) break;
      const int g = id / NTILN, nt = id % NTILN;
      const int tgt = (4*g + 4 < 79) ? 4*g + 4 : 79;
      wait_prog((unsigned)tgt);
      do_tile(g, nt);
    }
  };

  // ---------------- workers ----------------
  if (wg >= 32) { tile_pool(); return; }

  // ---------------- producer (r4/r5-proven recurrence) ----------------
  const int w = wg;
  _Float16* whh  = (_Float16*)smem;        // [48][520] fp16 (padded rows)
  _Float16* eo_l = whh + 48*520;           // [80][512] fp16
  _Float16* hsh  = eo_l + 80*512;          // [512]
  float* sc = (float*)(hsh + 512);         // [80]
  float* aw = sc + 80;                     // [80]

  const int lr = lane & 15;
  const int l4 = lane >> 4;           // 0..3
  const int b  = wv*16 + lr;          // batch this thread covers
  const int jc = w*16 + 4*l4;         // global h-col base (4 wide)

  auto loadW = [&](const float* W){
    for (int i = tid; i < 48*512; i += 128) {
      const int r = i >> 9, k = i & 511;
      whh[r*520 + k] = (_Float16)W[((size_t)(r>>4)*512 + w*16 + (r&15))*512 + k];
    }
  };
  auto wait_flags = [&](int buf, unsigned tgt){
    if (tid < 32) {
      while (__hip_atomic_load(&flags[(buf*32 + tid)*32], __ATOMIC_RELAXED,
                               __HIP_MEMORY_SCOPE_AGENT) < tgt)
        __builtin_amdgcn_s_sleep(1);
    }
    __syncthreads();
  };
  auto publish = [&](int buf, unsigned val){
    asm volatile("s_waitcnt vmcnt(0)" ::: "memory");   // all sc1 data stores done
    __syncthreads();
    if (tid == 0)
      __hip_atomic_store(&flags[(buf*32 + w)*32], val, __ATOMIC_RELAXED,
                         __HIP_MEMORY_SCOPE_AGENT);
  };

  const floatx4 ebr = *(const floatx4*)&ebhh[jc];
  const floatx4 ebz = *(const floatx4*)&ebhh[HH + jc];
  const floatx4 ebn = *(const floatx4*)&ebhh[2*HH + jc];
  const floatx4 dbr = *(const floatx4*)&dbhh[jc];
  const floatx4 dbz = *(const floatx4*)&dbhh[HH + jc];
  const floatx4 dbn = *(const floatx4*)&dbhh[2*HH + jc];

  float hp[4] = {0.f, 0.f, 0.f, 0.f};   // fp32 h_prev (batch b, cols jc..jc+3)

  auto gru = [&](floatx4 gr, floatx4 gz, floatx4 gn,
                 floatx4 bR, floatx4 bZ, floatx4 bN,
                 const u64* bufR, u64* bufW, _Float16* stash){
    const u64* hb = bufR + b*128 + l4*2;
    u64 hq[32];
#pragma unroll
    for (int kt = 0; kt < 16; ++kt) {
      hq[2*kt]   = aload(hb + kt*8);
      hq[2*kt+1] = aload(hb + kt*8 + 1);
    }
    u64 sq = 0;
    if (stash) sq = aload(bufR + w*128 + tid);
    floatx4 a0 = (floatx4){0.f,0.f,0.f,0.f}, a1 = a0, a2 = a0;
#pragma unroll
    for (int kt = 0; kt < 16; ++kt) {
      union { u64 q[2]; half8 v; } hu;
      hu.q[0] = hq[2*kt]; hu.q[1] = hq[2*kt+1];
      const int ko = kt*32 + l4*8;
      const half8 x0 = *(const half8*)&whh[(     lr)*520 + ko];
      const half8 x1 = *(const half8*)&whh[(16 + lr)*520 + ko];
      const half8 x2 = *(const half8*)&whh[(32 + lr)*520 + ko];
      a0 = __builtin_amdgcn_mfma_f32_16x16x32_f16(x0, hu.v, a0, 0,0,0);
      a1 = __builtin_amdgcn_mfma_f32_16x16x32_f16(x1, hu.v, a1, 0,0,0);
      a2 = __builtin_amdgcn_mfma_f32_16x16x32_f16(x2, hu.v, a2, 0,0,0);
    }
    union { u64 q; _Float16 h[4]; } hw;
#pragma unroll
    for (int r = 0; r < 4; ++r) {
      const float rg = sigm(gr[r] + a0[r] + bR[r]);
      const float zg = sigm(gz[r] + a1[r] + bZ[r]);
      const float ng = tanh_f(gn[r] + rg*(a2[r] + bN[r]));
      const float hn = (1.f - zg)*ng + zg*hp[r];
      hp[r] = hn;
      hw.h[r] = (_Float16)hn;
    }
    astore(bufW + b*128 + w*4 + l4, hw.q);
    if (stash) *(u64*)&stash[tid*4] = sq;
  };

  auto attention = [&](int trow){
    const half8 hf = *(const half8*)&hsh[lane*8];
#pragma unroll 4
    for (int i = 0; i < 40; ++i) {
      const int s = wv*40 + i;
      const half8 ev = *(const half8*)&eo_l[s*512 + lane*8];
      float pt = dot8(ev, hf, 0.f);
#pragma unroll
      for (int o = 32; o; o >>= 1) pt += __shfl_xor(pt, o);
      if (lane == 0) sc[s] = pt;
    }
    __syncthreads();
    if (wv == 0) {
      const float v0 = sc[lane];
      const float v1 = (lane < 16) ? sc[64+lane] : -1e30f;
      float m = fmaxf(v0, v1);
#pragma unroll
      for (int o = 32; o; o >>= 1) m = fmaxf(m, __shfl_xor(m, o));
      const float e0 = __expf(v0 - m);
      const float e1 = (lane < 16) ? __expf(v1 - m) : 0.f;
      float ssum = e0 + e1;
#pragma unroll
      for (int o = 32; o; o >>= 1) ssum += __shfl_xor(ssum, o);
      const float inv = 1.f/ssum;
      aw[lane] = e0*inv;
      if (lane < 16) aw[64+lane] = e1*inv;
    }
    __syncthreads();
    float c0=0.f, c1=0.f, c2=0.f, c3=0.f;
#pragma unroll 8
    for (int s = 0; s < SS; ++s) {
      const float a = aw[s];
      const half4 hv = *(const half4*)&eo_l[s*512 + tid*4];
      c0 += a*(float)hv[0]; c1 += a*(float)hv[1];
      c2 += a*(float)hv[2]; c3 += a*(float)hv[3];
    }
    // comb row (sc1 so workers see it) in [t][b] layout
    u64* crq = (u64*)(comb + (size_t)(trow*32 + w)*1024);
    astore(crq + tid, *(const u64*)&hsh[tid*4]);
    union { u64 q; _Float16 h[4]; } cu;
    cu.h[0]=(_Float16)c0; cu.h[1]=(_Float16)c1; cu.h[2]=(_Float16)c2; cu.h[3]=(_Float16)c3;
    astore(crq + 128 + tid, cu.q);
    asm volatile("s_waitcnt vmcnt(0)" ::: "memory");   // comb stores at LLC
    __syncthreads();
    if (tid == 0)
      __hip_atomic_store(prog + w*32, (unsigned)(trow+1), __ATOMIC_RELAXED,
                         __HIP_MEMORY_SCOPE_AGENT);
  };

  // init ping buffer 0 (own word), load enc weights, publish step 0
  astore((u64*)h16 + w*128 + tid, 0ull);
  loadW(eWhh);
  publish(0, 1);

  // -------- encoder: k = 0..79 --------
  for (int k = 0; k < SS; ++k) {
    const int p = k & 1;
    const float* girow = giE + (size_t)(b*SS + k)*1536 + jc;
    const floatx4 gr = *(const floatx4*)(girow);          // prefetch pre-wait
    const floatx4 gz = *(const floatx4*)(girow + HH);
    const floatx4 gn = *(const floatx4*)(girow + 2*HH);
    wait_flags(p, (unsigned)(k+1));
    gru(gr, gz, gn, ebr, ebz, ebn,
        (u64*)h16 + (size_t)p*(BB*HH/4), (u64*)h16 + (size_t)(1-p)*(BB*HH/4),
        (k > 0) ? (eo_l + (k-1)*512) : nullptr);
    publish(1-p, (unsigned)(k+2));
  }

  // -------- decoder: k = 80..158 (t = k-80) --------
  __syncthreads();
  loadW(dWhh);
  __syncthreads();
  for (int t = 0; t < TT-1; ++t) {
    const int k = 80 + t;
    const int p = k & 1;
    const float* girow = giD + (size_t)(b*79 + t)*1536 + jc;
    const floatx4 gr = *(const floatx4*)(girow);
    const floatx4 gz = *(const floatx4*)(girow + HH);
    const floatx4 gn = *(const floatx4*)(girow + 2*HH);
    wait_flags(p, (unsigned)(k+1));
    gru(gr, gz, gn, dbr, dbz, dbn,
        (u64*)h16 + (size_t)p*(BB*HH/4), (u64*)h16 + (size_t)(1-p)*(BB*HH/4),
        (t == 0) ? (eo_l + 79*512) : hsh);   // t=0: enc h(79); else h(t-1)
    publish(1-p, (unsigned)(k+2));
    if (t > 0) { __syncthreads(); attention(t-1); }
  }
  // final: attention(78) on h(158) (buffer 1, flag val 160) -> prog becomes 79
  wait_flags(1, 160u);
  {
    const u64 q = aload((const u64*)h16 + (size_t)1*(BB*HH/4) + w*128 + tid);
    *(u64*)&hsh[tid*4] = q;
  }
  __syncthreads();
  attention(TT-2);

  // -------- mop-up: help finish remaining logits tiles --------
  tile_pool();
}

extern "C" void kernel_launch(void* const* d_in, const int* in_sizes, int n_in,
                              void* d_out, int out_size, void* d_ws, size_t ws_size,
                              hipStream_t stream) {
  (void)in_sizes; (void)n_in; (void)out_size; (void)ws_size;
  const int*   src  = (const int*)d_in[0];
  const int*   tgt  = (const int*)d_in[1];
  const float* emb  = (const float*)d_in[2];
  const float* eWih = (const float*)d_in[3];
  const float* eWhh = (const float*)d_in[4];
  const float* ebih = (const float*)d_in[5];
  const float* ebhh = (const float*)d_in[6];
  const float* dWih = (const float*)d_in[7];
  const float* dWhh = (const float*)d_in[8];
  const float* dbih = (const float*)d_in[9];
  const float* dbhh = (const float*)d_in[10];
  const float* outW = (const float*)d_in[11];
  const float* outb = (const float*)d_in[12];
  float* out = (float*)d_out;

  char* p = (char*)d_ws;
  auto alloc = [&](size_t n){ char* r = p; p += (n + 255) & ~(size_t)255; return r; };
  _Float16* xsrc = (_Float16*)alloc((size_t)2560*256*2);
  _Float16* xdec = (_Float16*)alloc((size_t)2560*256*2);
  _Float16* wEh  = (_Float16*)alloc((size_t)1536*256*2);
  _Float16* wDh  = (_Float16*)alloc((size_t)1536*256*2);
  _Float16* oWh  = (_Float16*)alloc((size_t)VV*1024*2);
  float*    giE  = (float*)alloc((size_t)2560*1536*4);
  float*    giD  = (float*)alloc((size_t)2560*1536*4);
  _Float16* h16  = (_Float16*)alloc((size_t)2*BB*HH*2);   // ping-pong
  _Float16* comb = (_Float16*)alloc((size_t)2560*1024*2); // [t][b] layout
  unsigned* flags= (unsigned*)alloc(2*32*128);
  unsigned* prog = (unsigned*)alloc(32*128);
  unsigned* tick = (unsigned*)alloc(256);

  hipMemsetAsync(flags, 0, 2*32*128, stream);
  hipMemsetAsync(prog,  0, 32*128,   stream);
  hipMemsetAsync(tick,  0, 256,      stream);
  embed_gather<<<5120, 256, 0, stream>>>(src, tgt, emb, xsrc, xdec);
  wconv<<<2048, 256, 0, stream>>>(eWih, dWih, outW, wEh, wDh, oWh);
  mfma_gemm<<<dim3(12,20), 256, 0, stream>>>(xsrc, 256, wEh, 256, ebih, giE, 1536, 256);
  mfma_gemm<<<dim3(12,20), 256, 0, stream>>>(xdec, 256, wDh, 256, dbih, giD, 1536, 256);
  hipFuncSetAttribute((const void*)seq_over,
                      hipFuncAttributeMaxDynamicSharedMemorySize, SEQ_SMEM);
  seq_over<<<224, 128, SEQ_SMEM, stream>>>(eWhh, dWhh, ebhh, dbhh, giE, giD,
                                           h16, comb, flags, prog, tick,
                                           oWh, outb, out);
}

// Round 9
// 2263.195 us; speedup vs baseline: 1.0510x; 1.0510x over previous
//
#include <hip/hip_runtime.h>

#define VV 32000
#define EE 256
#define HH 512
#define BB 32
#define SS 80
#define TT 80
// decoder rows = B*(T-1) = 2528, padded to 2560 (20 tiles of 128)

typedef __attribute__((ext_vector_type(8))) _Float16 half8;
typedef __attribute__((ext_vector_type(4))) _Float16 half4;
typedef __attribute__((ext_vector_type(4))) float floatx4;
typedef unsigned long long u64;

__device__ __forceinline__ void gload16(const _Float16* g, _Float16* l) {
  __builtin_amdgcn_global_load_lds((const __attribute__((address_space(1))) void*)g,
                                   (__attribute__((address_space(3))) void*)l, 16, 0, 0);
}

__device__ __forceinline__ u64 aload(const u64* p) {
  return __hip_atomic_load(p, __ATOMIC_RELAXED, __HIP_MEMORY_SCOPE_AGENT);
}
__device__ __forceinline__ void astore(u64* p, u64 v) {
  __hip_atomic_store(p, v, __ATOMIC_RELAXED, __HIP_MEMORY_SCOPE_AGENT);
}

// ---- 15-bit packing: |h|<=1 so fp16 bits fit sign(b15->b14)+14 bits --------
// word = v0 | v1<<15 | v2<<30 | v3<<45 | tag<<60
__device__ __forceinline__ unsigned pack15(unsigned short u) {
  return (u & 0x3FFFu) | ((u >> 1) & 0x4000u);
}
__device__ __forceinline__ unsigned short unpack15(unsigned v) {
  return (unsigned short)((v & 0x3FFFu) | ((v & 0x4000u) << 1));
}
__device__ __forceinline__ half8 unpack2(u64 a, u64 b) {
  union { unsigned short us[8]; half8 v; } r;
#pragma unroll
  for (int i = 0; i < 4; ++i) {
    r.us[i]     = unpack15((unsigned)(a >> (15*i)) & 0x7FFFu);
    r.us[4 + i] = unpack15((unsigned)(b >> (15*i)) & 0x7FFFu);
  }
  return r.v;
}
__device__ __forceinline__ u64 unpack_word4(u64 a) {  // -> 4 fp16 in a u64
  u64 o = 0;
#pragma unroll
  for (int i = 0; i < 4; ++i)
    o |= (u64)unpack15((unsigned)(a >> (15*i)) & 0x7FFFu) << (16*i);
  return o;
}

__device__ __forceinline__ float dot8(half8 a, half8 b, float c) {
  typedef __attribute__((ext_vector_type(2))) _Float16 half2v;
  half2v a0 = {a[0],a[1]}, a1 = {a[2],a[3]}, a2 = {a[4],a[5]}, a3 = {a[6],a[7]};
  half2v b0 = {b[0],b[1]}, b1 = {b[2],b[3]}, b2 = {b[4],b[5]}, b3 = {b[6],b[7]};
  c = __builtin_amdgcn_fdot2(a0, b0, c, false);
  c = __builtin_amdgcn_fdot2(a1, b1, c, false);
  c = __builtin_amdgcn_fdot2(a2, b2, c, false);
  c = __builtin_amdgcn_fdot2(a3, b3, c, false);
  return c;
}

__device__ __forceinline__ float sigm(float x) { return 1.f/(1.f + __expf(-x)); }
__device__ __forceinline__ float tanh_f(float x) { return 2.f/(1.f + __expf(-2.f*x)) - 1.f; }

// ---------------- embedding gather (fp32 -> fp16 rows) ----------------
__global__ __launch_bounds__(256) void embed_gather(
    const int* __restrict__ src, const int* __restrict__ tgt,
    const float* __restrict__ emb,
    _Float16* __restrict__ xsrc, _Float16* __restrict__ xdec)
{
  const int r = blockIdx.x;
  const int e = threadIdx.x; // EE == 256
  if (r < 2560) {
    const int tok = src[r];
    xsrc[(size_t)r*EE + e] = (_Float16)emb[(size_t)tok*EE + e];
  } else {
    const int rr = r - 2560;
    if (rr < 2528) {
      const int b = rr / 79, t = rr - b*79;
      const int tok = tgt[b*TT + t];
      xdec[(size_t)rr*EE + e] = (_Float16)emb[(size_t)tok*EE + e];
    } else {
      xdec[(size_t)rr*EE + e] = (_Float16)0.f;
    }
  }
}

// ---------------- weight fp32 -> fp16 conversion (Wih, out_W) ----------------
__global__ __launch_bounds__(256) void wconv(
    const float* __restrict__ we, const float* __restrict__ wd, const float* __restrict__ ow,
    _Float16* __restrict__ weh, _Float16* __restrict__ wdh, _Float16* __restrict__ owh)
{
  const long n1 = 1536L*256;
  const long total = 2*n1 + (long)VV*1024;
  for (long i = (long)blockIdx.x*256 + threadIdx.x; i < total; i += (long)gridDim.x*256) {
    if (i < n1)           weh[i]        = (_Float16)we[i];
    else if (i < 2*n1)    wdh[i-n1]     = (_Float16)wd[i-n1];
    else                  owh[i-2*n1]   = (_Float16)ow[i-2*n1];
  }
}

// ---------------- generic fp16 MFMA GEMM: C(MxN) = A(MxK) * B(NxK)^T + bias ----
// MODE 0: C[row*ldc+col].
// MODE 1: logits scatter: row<2528 -> [b,t+1,:]; pad row 2528+b -> [b,0,:] = 0.
template<int MODE>
__global__ __launch_bounds__(256) void mfma_gemm(
    const _Float16* __restrict__ A, int lda,
    const _Float16* __restrict__ Bm, int ldb,
    const float* __restrict__ bias,
    float* __restrict__ Cout, int ldc, int K)
{
  __shared__ _Float16 As[4096];  // 128 x 32
  __shared__ _Float16 Bs[4096];  // 128 x 32
  const int tid = threadIdx.x;
  const int lane = tid & 63;
  const int wv = tid >> 6;
  const int wr = wv >> 1, wc = wv & 1;
  const int mt = blockIdx.y, nt = blockIdx.x;
  floatx4 acc[4][4];
#pragma unroll
  for (int i=0;i<4;++i)
#pragma unroll
    for (int j=0;j<4;++j) acc[i][j] = (floatx4){0.f,0.f,0.f,0.f};
  const int srow = lane >> 2;
  const int scol = (lane & 3) * 8;
  const _Float16* Ab = A + (size_t)(mt*128)*lda;
  const _Float16* Bb = Bm + (size_t)(nt*128)*ldb;
  const int g8 = (lane >> 4) * 8;
  const int lr = lane & 15;
  for (int kb = 0; kb < K; kb += 32) {
    __syncthreads();
#pragma unroll
    for (int cc = 0; cc < 2; ++cc) {
      const int c = wv*2 + cc;
      gload16(Ab + (size_t)(c*16 + srow)*lda + kb + scol, As + c*512);
      gload16(Bb + (size_t)(c*16 + srow)*ldb + kb + scol, Bs + c*512);
    }
    __syncthreads();
    half8 af[4], bf[4];
#pragma unroll
    for (int i=0;i<4;++i) af[i] = *(const half8*)(As + (wr*64 + i*16 + lr)*32 + g8);
#pragma unroll
    for (int j=0;j<4;++j) bf[j] = *(const half8*)(Bs + (wc*64 + j*16 + lr)*32 + g8);
#pragma unroll
    for (int i=0;i<4;++i)
#pragma unroll
      for (int j=0;j<4;++j)
        acc[i][j] = __builtin_amdgcn_mfma_f32_16x16x32_f16(af[i], bf[j], acc[i][j], 0,0,0);
  }
  const int rm = 4*(lane>>4);
#pragma unroll
  for (int i=0;i<4;++i) {
#pragma unroll
    for (int r=0;r<4;++r) {
      const int row = mt*128 + wr*64 + i*16 + rm + r;
#pragma unroll
      for (int j=0;j<4;++j) {
        const int col = nt*128 + wc*64 + j*16 + lr;
        const float v = acc[i][j][r] + bias[col];
        if (MODE == 0) {
          Cout[(size_t)row*ldc + col] = v;
        } else {
          if (row < 2528) {
            const int b = row / 79;
            const int t = row - b*79;
            Cout[(size_t)(b*80 + t + 1)*VV + col] = v;
          } else {
            Cout[(size_t)((row - 2528)*80)*VV + col] = 0.f;  // logits[b,0,:]=0
          }
        }
      }
    }
  }
}

// ---------------- fused recurrence: TAG-IN-DATA protocol (2 LLC hops) --------
// 32 WGs x 128 thr. WG w owns h cols [w*16,w*16+16); Whh slice in LDS.
// Each u64 h-word = 4x15-bit fp16 (|h|<=1 proven) + 4-bit step tag. Consumers
// poll words until tag==k&15 -- detection IS the data transfer. No flags, no
// vmcnt(0) on the critical path, no publish barrier. Slot k&1 read / (k+1)&1
// write; even tags only ever in slot 0, odd in slot 1, so memset-0 init is a
// valid h(-1) and a never-matching tag for slot 1. Write-after-read safety:
// producer overwrites h(k-2) only after consuming h(k-1); every WG published
// h(k-1) only after its h(k-2) loads COMPLETED (register data dependence),
// and the stash word is tag-verified before our h-store closes the window.
#define SEQ_SMEM ((48*520 + 80*512 + 512)*2 + 160*4)
__global__ __launch_bounds__(128) void seq_fused(
    const float* __restrict__ eWhh, const float* __restrict__ dWhh,
    const float* __restrict__ ebhh, const float* __restrict__ dbhh,
    const float* __restrict__ giE, const float* __restrict__ giD,
    _Float16* __restrict__ h16,    // ping-pong 2 x 32 x 512 fp16 (memset 0)
    _Float16* __restrict__ comb)
{
  extern __shared__ char smem[];
  _Float16* whh  = (_Float16*)smem;        // [48][520] fp16 (padded rows)
  _Float16* eo_l = whh + 48*520;           // [80][512] fp16
  _Float16* hsh  = eo_l + 80*512;          // [512]
  float* sc = (float*)(hsh + 512);         // [80]
  float* aw = sc + 80;                     // [80]

  const int w = blockIdx.x;
  const int tid = threadIdx.x;
  const int lane = tid & 63;
  const int wv = tid >> 6;            // 0..1 batch group
  const int lr = lane & 15;
  const int l4 = lane >> 4;           // 0..3
  const int b  = wv*16 + lr;          // batch this thread covers
  const int jc = w*16 + 4*l4;         // global h-col base (4 wide)

  auto loadW = [&](const float* W){
    for (int i = tid; i < 48*512; i += 128) {
      const int r = i >> 9, k = i & 511;
      whh[r*520 + k] = (_Float16)W[((size_t)(r>>4)*512 + w*16 + (r&15))*512 + k];
    }
  };

  const floatx4 ebr = *(const floatx4*)&ebhh[jc];
  const floatx4 ebz = *(const floatx4*)&ebhh[HH + jc];
  const floatx4 ebn = *(const floatx4*)&ebhh[2*HH + jc];
  const floatx4 dbr = *(const floatx4*)&dbhh[jc];
  const floatx4 dbz = *(const floatx4*)&dbhh[HH + jc];
  const floatx4 dbn = *(const floatx4*)&dbhh[2*HH + jc];

  float hp[4] = {0.f, 0.f, 0.f, 0.f};   // fp32 h_prev (batch b, cols jc..jc+3)

  // one step k: poll-consume bufR (tag rtag), MFMA+gates, store tagged word.
  auto gru = [&](floatx4 gr, floatx4 gz, floatx4 gn,
                 floatx4 bR, floatx4 bZ, floatx4 bN,
                 const u64* bufR, u64* bufW, u64 rtag, u64 wtag,
                 _Float16* stash){
    u64 sq = 0;
    if (stash) sq = aload(bufR + w*128 + tid);      // issue early (row w)
    const u64* hb = bufR + b*128 + l4*2;
    u64 hq[32];
#pragma unroll
    for (int kt = 0; kt < 16; ++kt) {
      hq[2*kt]   = aload(hb + kt*8);
      hq[2*kt+1] = aload(hb + kt*8 + 1);
    }
    for (;;) {                        // retry only stale-tag words
      bool again = false;
#pragma unroll
      for (int i = 0; i < 32; ++i) {
        if ((hq[i] >> 60) != rtag) {
          hq[i] = aload(hb + (i>>1)*8 + (i&1));
          again = true;
        }
      }
      if (!again) break;
    }
    floatx4 a0 = (floatx4){0.f,0.f,0.f,0.f}, a1 = a0, a2 = a0;
#pragma unroll
    for (int kt = 0; kt < 16; ++kt) {
      const half8 hv = unpack2(hq[2*kt], hq[2*kt+1]);
      const int ko = kt*32 + l4*8;
      const half8 x0 = *(const half8*)&whh[(     lr)*520 + ko];
      const half8 x1 = *(const half8*)&whh[(16 + lr)*520 + ko];
      const half8 x2 = *(const half8*)&whh[(32 + lr)*520 + ko];
      a0 = __builtin_amdgcn_mfma_f32_16x16x32_f16(x0, hv, a0, 0,0,0);
      a1 = __builtin_amdgcn_mfma_f32_16x16x32_f16(x1, hv, a1, 0,0,0);
      a2 = __builtin_amdgcn_mfma_f32_16x16x32_f16(x2, hv, a2, 0,0,0);
    }
    u64 wq = wtag << 60;
#pragma unroll
    for (int r = 0; r < 4; ++r) {
      const float rg = sigm(gr[r] + a0[r] + bR[r]);
      const float zg = sigm(gz[r] + a1[r] + bZ[r]);
      const float ng = tanh_f(gn[r] + rg*(a2[r] + bN[r]));
      const float hn = (1.f - zg)*ng + zg*hp[r];   // |hn| <= 1 by induction
      hp[r] = hn;
      union { _Float16 h; unsigned short u; } cv; cv.h = (_Float16)hn;
      wq |= (u64)pack15(cv.u) << (15*r);
    }
    if (stash) {                      // consume stash BEFORE publishing h
      while ((sq >> 60) != rtag) sq = aload(bufR + w*128 + tid);
      *(u64*)&stash[tid*4] = unpack_word4(sq);
    }
    astore(bufW + b*128 + w*4 + l4, wq);           // publish (tag makes valid)
  };

  auto attention = [&](int trow){
    const half8 hf = *(const half8*)&hsh[lane*8];
#pragma unroll 4
    for (int i = 0; i < 40; ++i) {
      const int s = wv*40 + i;
      const half8 ev = *(const half8*)&eo_l[s*512 + lane*8];
      float pt = dot8(ev, hf, 0.f);
#pragma unroll
      for (int o = 32; o; o >>= 1) pt += __shfl_xor(pt, o);
      if (lane == 0) sc[s] = pt;
    }
    __syncthreads();
    if (wv == 0) {
      const float v0 = sc[lane];
      const float v1 = (lane < 16) ? sc[64+lane] : -1e30f;
      float m = fmaxf(v0, v1);
#pragma unroll
      for (int o = 32; o; o >>= 1) m = fmaxf(m, __shfl_xor(m, o));
      const float e0 = __expf(v0 - m);
      const float e1 = (lane < 16) ? __expf(v1 - m) : 0.f;
      float ssum = e0 + e1;
#pragma unroll
      for (int o = 32; o; o >>= 1) ssum += __shfl_xor(ssum, o);
      const float inv = 1.f/ssum;
      aw[lane] = e0*inv;
      if (lane < 16) aw[64+lane] = e1*inv;
    }
    __syncthreads();
    float c0=0.f, c1=0.f, c2=0.f, c3=0.f;
#pragma unroll 8
    for (int s = 0; s < SS; ++s) {
      const float a = aw[s];
      const half4 hv = *(const half4*)&eo_l[s*512 + tid*4];
      c0 += a*(float)hv[0]; c1 += a*(float)hv[1];
      c2 += a*(float)hv[2]; c3 += a*(float)hv[3];
    }
    _Float16* cr = comb + ((size_t)w*79 + trow)*1024;
    *(u64*)&cr[tid*4] = *(const u64*)&hsh[tid*4];
    union { u64 q; _Float16 h[4]; } cu;
    cu.h[0]=(_Float16)c0; cu.h[1]=(_Float16)c1; cu.h[2]=(_Float16)c2; cu.h[3]=(_Float16)c3;
    *(u64*)&cr[512 + tid*4] = cu.q;
    __syncthreads();                  // hsh/sc/aw safe for reuse next iter
  };

  loadW(eWhh);
  __syncthreads();

  // -------- encoder: k = 0..79 (zero intra-WG barriers per step) --------
  for (int k = 0; k < SS; ++k) {
    const int p = k & 1;
    const float* girow = giE + (size_t)(b*SS + k)*1536 + jc;
    const floatx4 gr = *(const floatx4*)(girow);
    const floatx4 gz = *(const floatx4*)(girow + HH);
    const floatx4 gn = *(const floatx4*)(girow + 2*HH);
    gru(gr, gz, gn, ebr, ebz, ebn,
        (u64*)h16 + (size_t)p*(BB*HH/4), (u64*)h16 + (size_t)(1-p)*(BB*HH/4),
        (u64)(k & 15), (u64)((k+1) & 15),
        (k > 0) ? (eo_l + (k-1)*512) : nullptr);
  }

  // -------- decoder: k = 80..158 (t = k-80) --------
  __syncthreads();                    // both waves done with enc whh
  loadW(dWhh);
  __syncthreads();
  for (int t = 0; t < TT-1; ++t) {
    const int k = 80 + t;
    const int p = k & 1;
    const float* girow = giD + (size_t)(b*79 + t)*1536 + jc;
    const floatx4 gr = *(const floatx4*)(girow);
    const floatx4 gz = *(const floatx4*)(girow + HH);
    const floatx4 gn = *(const floatx4*)(girow + 2*HH);
    gru(gr, gz, gn, dbr, dbz, dbn,
        (u64*)h16 + (size_t)p*(BB*HH/4), (u64*)h16 + (size_t)(1-p)*(BB*HH/4),
        (u64)(k & 15), (u64)((k+1) & 15),
        (t == 0) ? (eo_l + 79*512) : hsh);   // t=0: enc h(79); else h(t-1)
    if (t > 0) { __syncthreads(); attention(t-1); }
  }
  // final: attention(78) on h(158): slot 1, tag 159&15 = 15
  {
    const u64* bufR = (u64*)h16 + (size_t)1*(BB*HH/4);
    u64 q = aload(bufR + w*128 + tid);
    while ((q >> 60) != 15ull) q = aload(bufR + w*128 + tid);
    *(u64*)&hsh[tid*4] = unpack_word4(q);
  }
  __syncthreads();
  attention(TT-2);
}

extern "C" void kernel_launch(void* const* d_in, const int* in_sizes, int n_in,
                              void* d_out, int out_size, void* d_ws, size_t ws_size,
                              hipStream_t stream) {
  (void)in_sizes; (void)n_in; (void)out_size; (void)ws_size;
  const int*   src  = (const int*)d_in[0];
  const int*   tgt  = (const int*)d_in[1];
  const float* emb  = (const float*)d_in[2];
  const float* eWih = (const float*)d_in[3];
  const float* eWhh = (const float*)d_in[4];
  const float* ebih = (const float*)d_in[5];
  const float* ebhh = (const float*)d_in[6];
  const float* dWih = (const float*)d_in[7];
  const float* dWhh = (const float*)d_in[8];
  const float* dbih = (const float*)d_in[9];
  const float* dbhh = (const float*)d_in[10];
  const float* outW = (const float*)d_in[11];
  const float* outb = (const float*)d_in[12];
  float* out = (float*)d_out;

  char* p = (char*)d_ws;
  auto alloc = [&](size_t n){ char* r = p; p += (n + 255) & ~(size_t)255; return r; };
  _Float16* xsrc = (_Float16*)alloc((size_t)2560*256*2);
  _Float16* xdec = (_Float16*)alloc((size_t)2560*256*2);
  _Float16* wEh  = (_Float16*)alloc((size_t)1536*256*2);
  _Float16* wDh  = (_Float16*)alloc((size_t)1536*256*2);
  _Float16* oWh  = (_Float16*)alloc((size_t)VV*1024*2);
  float*    giE  = (float*)alloc((size_t)2560*1536*4);
  float*    giD  = (float*)alloc((size_t)2560*1536*4);
  _Float16* h16  = (_Float16*)alloc((size_t)2*BB*HH*2);   // ping-pong, tagged
  _Float16* comb = (_Float16*)alloc((size_t)2560*1024*2);

  // slot 0 = h(-1) zeros (tag 0 valid); slot 1 = tag 0 (even) never matches
  hipMemsetAsync(h16, 0, (size_t)2*BB*HH*2, stream);

  embed_gather<<<5120, 256, 0, stream>>>(src, tgt, emb, xsrc, xdec);
  wconv<<<2048, 256, 0, stream>>>(eWih, dWih, outW, wEh, wDh, oWh);
  mfma_gemm<0><<<dim3(12,20), 256, 0, stream>>>(xsrc, 256, wEh, 256, ebih, giE, 1536, 256);
  mfma_gemm<0><<<dim3(12,20), 256, 0, stream>>>(xdec, 256, wDh, 256, dbih, giD, 1536, 256);
  hipFuncSetAttribute((const void*)seq_fused,
                      hipFuncAttributeMaxDynamicSharedMemorySize, SEQ_SMEM);
  seq_fused<<<32, 128, SEQ_SMEM, stream>>>(eWhh, dWhh, ebhh, dbhh, giE, giD,
                                           h16, comb);
  mfma_gemm<1><<<dim3(250,20), 256, 0, stream>>>(comb, 1024, oWh, 1024, outb, out, 0, 1024);
}

// Round 10
// 1904.344 us; speedup vs baseline: 1.2491x; 1.1884x over previous
//
#include <hip/hip_runtime.h>

#define VV 32000
#define EE 256
#define HH 512
#define BB 32
#define SS 80
#define TT 80
// decoder rows = B*(T-1) = 2528, padded to 2560 (20 tiles of 128)

typedef __attribute__((ext_vector_type(8))) _Float16 half8;
typedef __attribute__((ext_vector_type(4))) _Float16 half4;
typedef __attribute__((ext_vector_type(4))) float floatx4;
typedef unsigned long long u64;

__device__ __forceinline__ void gload16(const _Float16* g, _Float16* l) {
  __builtin_amdgcn_global_load_lds((const __attribute__((address_space(1))) void*)g,
                                   (__attribute__((address_space(3))) void*)l, 16, 0, 0);
}

__device__ __forceinline__ u64 aload(const u64* p) {
  return __hip_atomic_load(p, __ATOMIC_RELAXED, __HIP_MEMORY_SCOPE_AGENT);
}
__device__ __forceinline__ void astore(u64* p, u64 v) {
  __hip_atomic_store(p, v, __ATOMIC_RELAXED, __HIP_MEMORY_SCOPE_AGENT);
}

__device__ __forceinline__ float dot8(half8 a, half8 b, float c) {
  typedef __attribute__((ext_vector_type(2))) _Float16 half2v;
  half2v a0 = {a[0],a[1]}, a1 = {a[2],a[3]}, a2 = {a[4],a[5]}, a3 = {a[6],a[7]};
  half2v b0 = {b[0],b[1]}, b1 = {b[2],b[3]}, b2 = {b[4],b[5]}, b3 = {b[6],b[7]};
  c = __builtin_amdgcn_fdot2(a0, b0, c, false);
  c = __builtin_amdgcn_fdot2(a1, b1, c, false);
  c = __builtin_amdgcn_fdot2(a2, b2, c, false);
  c = __builtin_amdgcn_fdot2(a3, b3, c, false);
  return c;
}

__device__ __forceinline__ float sigm(float x) { return 1.f/(1.f + __expf(-x)); }
__device__ __forceinline__ float tanh_f(float x) { return 2.f/(1.f + __expf(-2.f*x)) - 1.f; }

// ---------------- embedding gather (fp32 -> fp16 rows) ----------------
__global__ __launch_bounds__(256) void embed_gather(
    const int* __restrict__ src, const int* __restrict__ tgt,
    const float* __restrict__ emb,
    _Float16* __restrict__ xsrc, _Float16* __restrict__ xdec)
{
  const int r = blockIdx.x;
  const int e = threadIdx.x; // EE == 256
  if (r < 2560) {
    const int tok = src[r];
    xsrc[(size_t)r*EE + e] = (_Float16)emb[(size_t)tok*EE + e];
  } else {
    const int rr = r - 2560;
    if (rr < 2528) {
      const int b = rr / 79, t = rr - b*79;
      const int tok = tgt[b*TT + t];
      xdec[(size_t)rr*EE + e] = (_Float16)emb[(size_t)tok*EE + e];
    } else {
      xdec[(size_t)rr*EE + e] = (_Float16)0.f;
    }
  }
}

// ---------------- weight fp32 -> fp16 conversion (Wih, out_W) ----------------
__global__ __launch_bounds__(256) void wconv(
    const float* __restrict__ we, const float* __restrict__ wd, const float* __restrict__ ow,
    _Float16* __restrict__ weh, _Float16* __restrict__ wdh, _Float16* __restrict__ owh)
{
  const long n1 = 1536L*256;
  const long total = 2*n1 + (long)VV*1024;
  for (long i = (long)blockIdx.x*256 + threadIdx.x; i < total; i += (long)gridDim.x*256) {
    if (i < n1)           weh[i]        = (_Float16)we[i];
    else if (i < 2*n1)    wdh[i-n1]     = (_Float16)wd[i-n1];
    else                  owh[i-2*n1]   = (_Float16)ow[i-2*n1];
  }
}

// ---------------- generic fp16 MFMA GEMM: C(MxN) = A(MxK) * B(NxK)^T + bias ----
// MODE 0: C[row*ldc+col].
// MODE 1: logits scatter: row<2528 -> [b,t+1,:]; pad row 2528+b -> [b,0,:] = 0.
template<int MODE>
__global__ __launch_bounds__(256) void mfma_gemm(
    const _Float16* __restrict__ A, int lda,
    const _Float16* __restrict__ Bm, int ldb,
    const float* __restrict__ bias,
    float* __restrict__ Cout, int ldc, int K)
{
  __shared__ _Float16 As[4096];  // 128 x 32
  __shared__ _Float16 Bs[4096];  // 128 x 32
  const int tid = threadIdx.x;
  const int lane = tid & 63;
  const int wv = tid >> 6;
  const int wr = wv >> 1, wc = wv & 1;
  const int mt = blockIdx.y, nt = blockIdx.x;
  floatx4 acc[4][4];
#pragma unroll
  for (int i=0;i<4;++i)
#pragma unroll
    for (int j=0;j<4;++j) acc[i][j] = (floatx4){0.f,0.f,0.f,0.f};
  const int srow = lane >> 2;
  const int scol = (lane & 3) * 8;
  const _Float16* Ab = A + (size_t)(mt*128)*lda;
  const _Float16* Bb = Bm + (size_t)(nt*128)*ldb;
  const int g8 = (lane >> 4) * 8;
  const int lr = lane & 15;
  for (int kb = 0; kb < K; kb += 32) {
    __syncthreads();
#pragma unroll
    for (int cc = 0; cc < 2; ++cc) {
      const int c = wv*2 + cc;
      gload16(Ab + (size_t)(c*16 + srow)*lda + kb + scol, As + c*512);
      gload16(Bb + (size_t)(c*16 + srow)*ldb + kb + scol, Bs + c*512);
    }
    __syncthreads();
    half8 af[4], bf[4];
#pragma unroll
    for (int i=0;i<4;++i) af[i] = *(const half8*)(As + (wr*64 + i*16 + lr)*32 + g8);
#pragma unroll
    for (int j=0;j<4;++j) bf[j] = *(const half8*)(Bs + (wc*64 + j*16 + lr)*32 + g8);
#pragma unroll
    for (int i=0;i<4;++i)
#pragma unroll
      for (int j=0;j<4;++j)
        acc[i][j] = __builtin_amdgcn_mfma_f32_16x16x32_f16(af[i], bf[j], acc[i][j], 0,0,0);
  }
  const int rm = 4*(lane>>4);
#pragma unroll
  for (int i=0;i<4;++i) {
#pragma unroll
    for (int r=0;r<4;++r) {
      const int row = mt*128 + wr*64 + i*16 + rm + r;
#pragma unroll
      for (int j=0;j<4;++j) {
        const int col = nt*128 + wc*64 + j*16 + lr;
        const float v = acc[i][j][r] + bias[col];
        if (MODE == 0) {
          Cout[(size_t)row*ldc + col] = v;
        } else {
          if (row < 2528) {
            const int b = row / 79;
            const int t = row - b*79;
            Cout[(size_t)(b*80 + t + 1)*VV + col] = v;
          } else {
            Cout[(size_t)((row - 2528)*80)*VV + col] = 0.f;  // logits[b,0,:]=0
          }
        }
      }
    }
  }
}

// ---------------- fused recurrence + clock heaters ---------------------------
// Grid 224 x 128 thr.
//   WGs 0..31  : producers -- EXACT r5 distributed-flags recurrence (proven
//                1582us): sc1 h ping-pong, per-WG monotone flag lines,
//                deferred attention. At the very end each adds to `done`.
//   WGs 32..223: heaters -- dependent-FMA chains (pure VALU, no memory) to
//                keep DPM clocks boosted during the latency-bound recurrence.
//                Exit when done==32 (checked once per chunk) or after a hard
//                chunk cap. Heaters write nothing -> deterministic output.
// Deadlock-safe: producers never wait on heaters; producers are WGs 0..31
// (dispatched first); heaters always terminate via the cap.
#define SEQ_SMEM ((48*520 + 80*512 + 512)*2 + 160*4)
__global__ __launch_bounds__(128) void seq_heat(
    const float* __restrict__ eWhh, const float* __restrict__ dWhh,
    const float* __restrict__ ebhh, const float* __restrict__ dbhh,
    const float* __restrict__ giE, const float* __restrict__ giD,
    _Float16* __restrict__ h16,    // ping-pong 2 x 32 x 512 fp16
    _Float16* __restrict__ comb,
    unsigned* __restrict__ flags,  // [2][32] monotone counters, 128B apart
    unsigned* __restrict__ done)   // producers-finished counter
{
  const int wg  = blockIdx.x;
  const int tid = threadIdx.x;

  // ---------------- heaters ----------------
  if (wg >= 32) {
    float x0 = 1.0f + (float)tid, x1 = 2.0f, x2 = 3.0f, x3 = 4.0f;
    for (int it = 0; it < 256; ++it) {           // hard cap ~0.5ms @2.4GHz
#pragma unroll 4
      for (int i = 0; i < 1024; ++i) {           // 4 indep chains, 4096 FMAs
        x0 = __builtin_fmaf(x0, 0.99993f, 0.00017f);
        x1 = __builtin_fmaf(x1, 0.99991f, 0.00023f);
        x2 = __builtin_fmaf(x2, 0.99989f, 0.00029f);
        x3 = __builtin_fmaf(x3, 0.99987f, 0.00031f);
      }
      if (__hip_atomic_load(done, __ATOMIC_RELAXED, __HIP_MEMORY_SCOPE_AGENT) >= 32u)
        break;
    }
    asm volatile("" :: "v"(x0), "v"(x1), "v"(x2), "v"(x3));  // keep live
    return;
  }

  // ---------------- producer (exact r5 recurrence) ----------------
  extern __shared__ char smem[];
  _Float16* whh  = (_Float16*)smem;        // [48][520] fp16 (padded rows)
  _Float16* eo_l = whh + 48*520;           // [80][512] fp16
  _Float16* hsh  = eo_l + 80*512;          // [512]
  float* sc = (float*)(hsh + 512);         // [80]
  float* aw = sc + 80;                     // [80]

  const int w = wg;
  const int lane = tid & 63;
  const int wv = tid >> 6;            // 0..1 batch group
  const int lr = lane & 15;
  const int l4 = lane >> 4;           // 0..3
  const int b  = wv*16 + lr;          // batch this thread covers
  const int jc = w*16 + 4*l4;         // global h-col base (4 wide)

  auto loadW = [&](const float* W){
    for (int i = tid; i < 48*512; i += 128) {
      const int r = i >> 9, k = i & 511;
      whh[r*520 + k] = (_Float16)W[((size_t)(r>>4)*512 + w*16 + (r&15))*512 + k];
    }
  };
  auto wait_flags = [&](int buf, unsigned tgt){
    if (tid < 32) {
      while (__hip_atomic_load(&flags[(buf*32 + tid)*32], __ATOMIC_RELAXED,
                               __HIP_MEMORY_SCOPE_AGENT) < tgt)
        __builtin_amdgcn_s_sleep(1);
    }
    __syncthreads();
  };
  auto publish = [&](int buf, unsigned val){
    asm volatile("s_waitcnt vmcnt(0)" ::: "memory");   // all sc1 data stores done
    __syncthreads();
    if (tid == 0)
      __hip_atomic_store(&flags[(buf*32 + w)*32], val, __ATOMIC_RELAXED,
                         __HIP_MEMORY_SCOPE_AGENT);
  };

  const floatx4 ebr = *(const floatx4*)&ebhh[jc];
  const floatx4 ebz = *(const floatx4*)&ebhh[HH + jc];
  const floatx4 ebn = *(const floatx4*)&ebhh[2*HH + jc];
  const floatx4 dbr = *(const floatx4*)&dbhh[jc];
  const floatx4 dbz = *(const floatx4*)&dbhh[HH + jc];
  const floatx4 dbn = *(const floatx4*)&dbhh[2*HH + jc];

  float hp[4] = {0.f, 0.f, 0.f, 0.f};   // fp32 h_prev (batch b, cols jc..jc+3)

  auto gru = [&](floatx4 gr, floatx4 gz, floatx4 gn,
                 floatx4 bR, floatx4 bZ, floatx4 bN,
                 const u64* bufR, u64* bufW, _Float16* stash){
    const u64* hb = bufR + b*128 + l4*2;
    u64 hq[32];
#pragma unroll
    for (int kt = 0; kt < 16; ++kt) {
      hq[2*kt]   = aload(hb + kt*8);
      hq[2*kt+1] = aload(hb + kt*8 + 1);
    }
    u64 sq = 0;
    if (stash) sq = aload(bufR + w*128 + tid);
    floatx4 a0 = (floatx4){0.f,0.f,0.f,0.f}, a1 = a0, a2 = a0;
#pragma unroll
    for (int kt = 0; kt < 16; ++kt) {
      union { u64 q[2]; half8 v; } hu;
      hu.q[0] = hq[2*kt]; hu.q[1] = hq[2*kt+1];
      const int ko = kt*32 + l4*8;
      const half8 x0 = *(const half8*)&whh[(     lr)*520 + ko];
      const half8 x1 = *(const half8*)&whh[(16 + lr)*520 + ko];
      const half8 x2 = *(const half8*)&whh[(32 + lr)*520 + ko];
      a0 = __builtin_amdgcn_mfma_f32_16x16x32_f16(x0, hu.v, a0, 0,0,0);
      a1 = __builtin_amdgcn_mfma_f32_16x16x32_f16(x1, hu.v, a1, 0,0,0);
      a2 = __builtin_amdgcn_mfma_f32_16x16x32_f16(x2, hu.v, a2, 0,0,0);
    }
    union { u64 q; _Float16 h[4]; } hw;
#pragma unroll
    for (int r = 0; r < 4; ++r) {
      const float rg = sigm(gr[r] + a0[r] + bR[r]);
      const float zg = sigm(gz[r] + a1[r] + bZ[r]);
      const float ng = tanh_f(gn[r] + rg*(a2[r] + bN[r]));
      const float hn = (1.f - zg)*ng + zg*hp[r];
      hp[r] = hn;
      hw.h[r] = (_Float16)hn;
    }
    astore(bufW + b*128 + w*4 + l4, hw.q);
    if (stash) *(u64*)&stash[tid*4] = sq;
  };

  auto attention = [&](int trow){
    const half8 hf = *(const half8*)&hsh[lane*8];
#pragma unroll 4
    for (int i = 0; i < 40; ++i) {
      const int s = wv*40 + i;
      const half8 ev = *(const half8*)&eo_l[s*512 + lane*8];
      float pt = dot8(ev, hf, 0.f);
#pragma unroll
      for (int o = 32; o; o >>= 1) pt += __shfl_xor(pt, o);
      if (lane == 0) sc[s] = pt;
    }
    __syncthreads();
    if (wv == 0) {
      const float v0 = sc[lane];
      const float v1 = (lane < 16) ? sc[64+lane] : -1e30f;
      float m = fmaxf(v0, v1);
#pragma unroll
      for (int o = 32; o; o >>= 1) m = fmaxf(m, __shfl_xor(m, o));
      const float e0 = __expf(v0 - m);
      const float e1 = (lane < 16) ? __expf(v1 - m) : 0.f;
      float ssum = e0 + e1;
#pragma unroll
      for (int o = 32; o; o >>= 1) ssum += __shfl_xor(ssum, o);
      const float inv = 1.f/ssum;
      aw[lane] = e0*inv;
      if (lane < 16) aw[64+lane] = e1*inv;
    }
    __syncthreads();
    float c0=0.f, c1=0.f, c2=0.f, c3=0.f;
#pragma unroll 8
    for (int s = 0; s < SS; ++s) {
      const float a = aw[s];
      const half4 hv = *(const half4*)&eo_l[s*512 + tid*4];
      c0 += a*(float)hv[0]; c1 += a*(float)hv[1];
      c2 += a*(float)hv[2]; c3 += a*(float)hv[3];
    }
    _Float16* cr = comb + ((size_t)w*79 + trow)*1024;
    *(u64*)&cr[tid*4] = *(const u64*)&hsh[tid*4];
    union { u64 q; _Float16 h[4]; } cu;
    cu.h[0]=(_Float16)c0; cu.h[1]=(_Float16)c1; cu.h[2]=(_Float16)c2; cu.h[3]=(_Float16)c3;
    *(u64*)&cr[512 + tid*4] = cu.q;
  };

  // init ping buffer 0 (own word), load enc weights, publish step 0
  astore((u64*)h16 + w*128 + tid, 0ull);
  loadW(eWhh);
  publish(0, 1);

  // -------- encoder: k = 0..79 --------
  for (int k = 0; k < SS; ++k) {
    const int p = k & 1;
    const float* girow = giE + (size_t)(b*SS + k)*1536 + jc;
    const floatx4 gr = *(const floatx4*)(girow);          // prefetch pre-wait
    const floatx4 gz = *(const floatx4*)(girow + HH);
    const floatx4 gn = *(const floatx4*)(girow + 2*HH);
    wait_flags(p, (unsigned)(k+1));
    gru(gr, gz, gn, ebr, ebz, ebn,
        (u64*)h16 + (size_t)p*(BB*HH/4), (u64*)h16 + (size_t)(1-p)*(BB*HH/4),
        (k > 0) ? (eo_l + (k-1)*512) : nullptr);
    publish(1-p, (unsigned)(k+2));
  }

  // -------- decoder: k = 80..158 (t = k-80) --------
  __syncthreads();
  loadW(dWhh);
  __syncthreads();
  for (int t = 0; t < TT-1; ++t) {
    const int k = 80 + t;
    const int p = k & 1;
    const float* girow = giD + (size_t)(b*79 + t)*1536 + jc;
    const floatx4 gr = *(const floatx4*)(girow);
    const floatx4 gz = *(const floatx4*)(girow + HH);
    const floatx4 gn = *(const floatx4*)(girow + 2*HH);
    wait_flags(p, (unsigned)(k+1));
    gru(gr, gz, gn, dbr, dbz, dbn,
        (u64*)h16 + (size_t)p*(BB*HH/4), (u64*)h16 + (size_t)(1-p)*(BB*HH/4),
        (t == 0) ? (eo_l + 79*512) : hsh);   // t=0: enc h(79); else h(t-1)
    publish(1-p, (unsigned)(k+2));
    if (t > 0) { __syncthreads(); attention(t-1); }
  }
  // final: attention(78) on h(158) (buffer 1, flag val 160)
  wait_flags(1, 160u);
  {
    const u64 q = aload((const u64*)h16 + (size_t)1*(BB*HH/4) + w*128 + tid);
    *(u64*)&hsh[tid*4] = q;
  }
  __syncthreads();
  attention(TT-2);

  // signal heaters
  __syncthreads();
  if (tid == 0)
    __hip_atomic_fetch_add(done, 1u, __ATOMIC_RELAXED, __HIP_MEMORY_SCOPE_AGENT);
}

extern "C" void kernel_launch(void* const* d_in, const int* in_sizes, int n_in,
                              void* d_out, int out_size, void* d_ws, size_t ws_size,
                              hipStream_t stream) {
  (void)in_sizes; (void)n_in; (void)out_size; (void)ws_size;
  const int*   src  = (const int*)d_in[0];
  const int*   tgt  = (const int*)d_in[1];
  const float* emb  = (const float*)d_in[2];
  const float* eWih = (const float*)d_in[3];
  const float* eWhh = (const float*)d_in[4];
  const float* ebih = (const float*)d_in[5];
  const float* ebhh = (const float*)d_in[6];
  const float* dWih = (const float*)d_in[7];
  const float* dWhh = (const float*)d_in[8];
  const float* dbih = (const float*)d_in[9];
  const float* dbhh = (const float*)d_in[10];
  const float* outW = (const float*)d_in[11];
  const float* outb = (const float*)d_in[12];
  float* out = (float*)d_out;

  char* p = (char*)d_ws;
  auto alloc = [&](size_t n){ char* r = p; p += (n + 255) & ~(size_t)255; return r; };
  _Float16* xsrc = (_Float16*)alloc((size_t)2560*256*2);
  _Float16* xdec = (_Float16*)alloc((size_t)2560*256*2);
  _Float16* wEh  = (_Float16*)alloc((size_t)1536*256*2);
  _Float16* wDh  = (_Float16*)alloc((size_t)1536*256*2);
  _Float16* oWh  = (_Float16*)alloc((size_t)VV*1024*2);
  float*    giE  = (float*)alloc((size_t)2560*1536*4);
  float*    giD  = (float*)alloc((size_t)2560*1536*4);
  _Float16* h16  = (_Float16*)alloc((size_t)2*BB*HH*2);   // ping-pong
  _Float16* comb = (_Float16*)alloc((size_t)2560*1024*2);
  unsigned* flags= (unsigned*)alloc(2*32*128);
  unsigned* done = (unsigned*)alloc(256);

  hipMemsetAsync(flags, 0, 2*32*128, stream);
  hipMemsetAsync(done,  0, 256,      stream);
  embed_gather<<<5120, 256, 0, stream>>>(src, tgt, emb, xsrc, xdec);
  wconv<<<2048, 256, 0, stream>>>(eWih, dWih, outW, wEh, wDh, oWh);
  mfma_gemm<0><<<dim3(12,20), 256, 0, stream>>>(xsrc, 256, wEh, 256, ebih, giE, 1536, 256);
  mfma_gemm<0><<<dim3(12,20), 256, 0, stream>>>(xdec, 256, wDh, 256, dbih, giD, 1536, 256);
  hipFuncSetAttribute((const void*)seq_heat,
                      hipFuncAttributeMaxDynamicSharedMemorySize, SEQ_SMEM);
  seq_heat<<<224, 128, SEQ_SMEM, stream>>>(eWhh, dWhh, ebhh, dbhh, giE, giD,
                                           h16, comb, flags, done);
  mfma_gemm<1><<<dim3(250,20), 256, 0, stream>>>(comb, 1024, oWh, 1024, outb, out, 0, 1024);
}